// Round 1
// baseline (728.022 us; speedup 1.0000x reference)
//
#include <hip/hip_runtime.h>
#include <hip/hip_bf16.h>
#include <math.h>

// GAT 2-layer forward for MI355X.
// Layer1: h1 = x@W1 [N,256]; a_s/a_d per head; segment-softmax over incoming
// edges (CSR by dst); out1 = sum alpha*h1[src]; elu(out1+b1) -> x1e.
// Layer2: h2 = x1e@W2 [N,64]; same with H=1; out2 + b2 -> log_softmax.

#define FIN 128
#define C1 256   // H*D layer1
#define NH 8
#define HD 32
#define C2 64    // F_out
#define TM1 16
#define CH1 64

__global__ void zero_kernel(int* p, int n) {
    int i = blockIdx.x * 256 + threadIdx.x;
    if (i < n) p[i] = 0;
}

__global__ void hist_kernel(const int* __restrict__ ei, int E, int ETOT, int* cnt) {
    int e = blockIdx.x * 256 + threadIdx.x;
    if (e >= ETOT) return;
    int dst = (e < E) ? ei[E + e] : (e - E);
    atomicAdd(&cnt[dst], 1);
}

// 1024-thread single-block scan: exclusive prefix over cnt[0..n) -> rowptr, cursor
__global__ void scan_kernel(const int* __restrict__ cnt, int* rowptr, int* cursor,
                            int n, int ETOT) {
    __shared__ int wsum[16];
    __shared__ int carry_s;
    __shared__ int tot_s;
    int tid = threadIdx.x, lane = tid & 63, w = tid >> 6;
    if (tid == 0) carry_s = 0;
    __syncthreads();
    for (int base = 0; base < n; base += 1024) {
        int i = base + tid;
        int v = (i < n) ? cnt[i] : 0;
        int sc = v;
        #pragma unroll
        for (int d = 1; d < 64; d <<= 1) {
            int t = __shfl_up(sc, d, 64);
            if (lane >= d) sc += t;
        }
        if (lane == 63) wsum[w] = sc;
        __syncthreads();
        if (w == 0 && lane < 16) {
            int t = wsum[lane];
            int s2 = t;
            #pragma unroll
            for (int d = 1; d < 16; d <<= 1) {
                int u = __shfl_up(s2, d, 64);
                if (lane >= d) s2 += u;
            }
            if (lane == 15) tot_s = s2;
            wsum[lane] = s2 - t;   // exclusive wave offset
        }
        __syncthreads();
        int excl = carry_s + wsum[w] + (sc - v);
        if (i < n) { rowptr[i] = excl; cursor[i] = excl; }
        __syncthreads();
        if (tid == 0) carry_s += tot_s;
        __syncthreads();
    }
    if (tid == 0) rowptr[n] = ETOT;
}

__global__ void scatter_kernel(const int* __restrict__ ei, int E, int ETOT,
                               int* cursor, int* colb) {
    int e = blockIdx.x * 256 + threadIdx.x;
    if (e >= ETOT) return;
    int src, dst;
    if (e < E) { src = ei[e]; dst = ei[E + e]; }
    else       { src = e - E; dst = e - E; }
    int pos = atomicAdd(&cursor[dst], 1);
    colb[pos] = src;
}

// h1 = x @ W1  [N,256]  (no bias), plus a_s1/a_d1 per (node, head)
__global__ __launch_bounds__(256) void gemm1_kernel(
    const float* __restrict__ x, const float* __restrict__ W1,
    const float* __restrict__ att_s, const float* __restrict__ att_d,
    float* __restrict__ h1, float* __restrict__ as1, float* __restrict__ ad1, int N) {
    __shared__ float xs[TM1][FIN];
    int tid = threadIdx.x;
    int row0 = blockIdx.x * TM1;
    #pragma unroll
    for (int i = 0; i < 8; ++i) {
        int f = tid + i * 256;
        int r = f >> 7, k = f & 127;
        int gr = row0 + r;
        xs[r][k] = (gr < N) ? x[(size_t)gr * FIN + k] : 0.f;
    }
    __syncthreads();
    float acc[TM1];
    #pragma unroll
    for (int r = 0; r < TM1; ++r) acc[r] = 0.f;
    const int j = tid;
    for (int k = 0; k < FIN; k += 4) {
        float w0 = W1[(size_t)(k + 0) * C1 + j];
        float w1 = W1[(size_t)(k + 1) * C1 + j];
        float w2 = W1[(size_t)(k + 2) * C1 + j];
        float w3 = W1[(size_t)(k + 3) * C1 + j];
        #pragma unroll
        for (int r = 0; r < TM1; ++r) {
            float4 xv = *reinterpret_cast<const float4*>(&xs[r][k]);
            acc[r] = fmaf(xv.x, w0, acc[r]);
            acc[r] = fmaf(xv.y, w1, acc[r]);
            acc[r] = fmaf(xv.z, w2, acc[r]);
            acc[r] = fmaf(xv.w, w3, acc[r]);
        }
    }
    int hd = j >> 5, d = j & 31;
    float asw = att_s[hd * HD + d], adw = att_d[hd * HD + d];
    #pragma unroll
    for (int r = 0; r < TM1; ++r) {
        int row = row0 + r;
        if (row >= N) break;
        float v = acc[r];
        h1[(size_t)row * C1 + j] = v;
        float ps = v * asw, pd = v * adw;
        #pragma unroll
        for (int m = 16; m >= 1; m >>= 1) {
            ps += __shfl_xor(ps, m, 64);
            pd += __shfl_xor(pd, m, 64);
        }
        if (d == 0) { as1[row * NH + hd] = ps; ad1[row * NH + hd] = pd; }
    }
}

// Layer-1 aggregation: one block per node; online segment softmax + gather-sum.
__global__ __launch_bounds__(256) void agg1_kernel(
    const int* __restrict__ rowptr, const int* __restrict__ colb,
    const float* __restrict__ as1, const float* __restrict__ ad1,
    const float* __restrict__ h1, const float* __restrict__ b1,
    float* __restrict__ x1e, int N) {
    int n = blockIdx.x;
    int tid = threadIdx.x, hd = tid >> 5, d = tid & 31;
    int start = rowptr[n], end = rowptr[n + 1];
    __shared__ float sp[CH1 * 9];      // per-edge per-head logits then p; stride 9 (bank-conflict-free)
    __shared__ int ssrc[CH1];
    __shared__ float adv[NH];
    if (tid < NH) adv[tid] = ad1[n * NH + tid];
    __syncthreads();
    float advr[NH];
    #pragma unroll
    for (int h = 0; h < NH; ++h) advr[h] = adv[h];

    float m = -INFINITY, denom = 0.f, acc = 0.f;
    for (int base = start; base < end; base += CH1) {
        int cn = min(CH1, end - base);
        if (tid < cn) {
            int s = colb[base + tid];
            ssrc[tid] = s;
            const float4* ap = reinterpret_cast<const float4*>(as1 + (size_t)s * NH);
            float4 a0 = ap[0], a1 = ap[1];
            float av[8] = {a0.x, a0.y, a0.z, a0.w, a1.x, a1.y, a1.z, a1.w};
            #pragma unroll
            for (int h = 0; h < NH; ++h) {
                float e = av[h] + advr[h];
                e = e > 0.f ? e : 0.2f * e;
                sp[tid * 9 + h] = e;
            }
        }
        __syncthreads();
        // per-head chunk max
        float cmax = -INFINITY;
        for (int e = d; e < cn; e += 32) cmax = fmaxf(cmax, sp[e * 9 + hd]);
        #pragma unroll
        for (int mk = 16; mk >= 1; mk >>= 1) cmax = fmaxf(cmax, __shfl_xor(cmax, mk, 64));
        float newm = fmaxf(m, cmax);
        float scale = __expf(m - newm);     // m=-inf -> 0
        acc *= scale; denom *= scale; m = newm;
        // p = exp(logit - m), overwrite in LDS (same wave-half, no barrier needed)
        float psum = 0.f;
        for (int e = d; e < cn; e += 32) {
            float p = __expf(sp[e * 9 + hd] - m);
            sp[e * 9 + hd] = p;
            psum += p;
        }
        #pragma unroll
        for (int mk = 16; mk >= 1; mk >>= 1) psum += __shfl_xor(psum, mk, 64);
        denom += psum;
        // gather-accumulate: coalesced 1KB row reads of h1[src]
        float accl = acc;
        for (int e = 0; e < cn; ++e) {
            float p = sp[e * 9 + hd];
            const float* hrow = h1 + (size_t)ssrc[e] * C1;
            accl = fmaf(p, hrow[tid], accl);
        }
        acc = accl;
        __syncthreads();   // before next chunk overwrites sp/ssrc
    }
    float outv = acc / denom + b1[tid];
    x1e[(size_t)n * C1 + tid] = outv > 0.f ? outv : __expf(outv) - 1.f;
}

// h2 = x1e @ W2 [N,64] (no bias), plus a_s2/a_d2 (H=1)
__global__ __launch_bounds__(256) void gemm2_kernel(
    const float* __restrict__ x1e, const float* __restrict__ W2,
    const float* __restrict__ att_s2, const float* __restrict__ att_d2,
    float* __restrict__ h2, float* __restrict__ as2, float* __restrict__ ad2, int N) {
    __shared__ float xs[16][C1];
    int tid = threadIdx.x;
    int row0 = blockIdx.x * 16;
    #pragma unroll
    for (int i = 0; i < 16; ++i) {
        int f = tid + i * 256;
        int r = f >> 8, k = f & 255;
        int gr = row0 + r;
        xs[r][k] = (gr < N) ? x1e[(size_t)gr * C1 + k] : 0.f;
    }
    __syncthreads();
    int j = tid & 63, rg = tid >> 6;   // wave rg handles rows rg*4..rg*4+3, cols 0..63
    float acc[4] = {0.f, 0.f, 0.f, 0.f};
    for (int k = 0; k < C1; k += 4) {
        float w0 = W2[(size_t)(k + 0) * C2 + j];
        float w1 = W2[(size_t)(k + 1) * C2 + j];
        float w2v = W2[(size_t)(k + 2) * C2 + j];
        float w3 = W2[(size_t)(k + 3) * C2 + j];
        #pragma unroll
        for (int r = 0; r < 4; ++r) {
            float4 xv = *reinterpret_cast<const float4*>(&xs[rg * 4 + r][k]);
            acc[r] = fmaf(xv.x, w0, acc[r]);
            acc[r] = fmaf(xv.y, w1, acc[r]);
            acc[r] = fmaf(xv.z, w2v, acc[r]);
            acc[r] = fmaf(xv.w, w3, acc[r]);
        }
    }
    float asw = att_s2[j], adw = att_d2[j];
    #pragma unroll
    for (int r = 0; r < 4; ++r) {
        int row = row0 + rg * 4 + r;
        if (row >= N) break;
        float v = acc[r];
        h2[(size_t)row * C2 + j] = v;
        float ps = v * asw, pd = v * adw;
        #pragma unroll
        for (int m = 32; m >= 1; m >>= 1) {
            ps += __shfl_xor(ps, m, 64);
            pd += __shfl_xor(pd, m, 64);
        }
        if (j == 0) { as2[row] = ps; ad2[row] = pd; }
    }
}

// Layer-2 aggregation + bias + log_softmax. One 64-lane wave per node.
__global__ __launch_bounds__(256) void agg2_kernel(
    const int* __restrict__ rowptr, const int* __restrict__ colb,
    const float* __restrict__ as2, const float* __restrict__ ad2,
    const float* __restrict__ h2, const float* __restrict__ b2,
    float* __restrict__ out, int N) {
    int wid = threadIdx.x >> 6, lane = threadIdx.x & 63;
    int n = blockIdx.x * 4 + wid;
    if (n >= N) return;
    int start = rowptr[n], end = rowptr[n + 1];
    float adn = ad2[n];
    float m = -INFINITY, denom = 0.f, acc = 0.f;
    for (int base = start; base < end; base += 64) {
        int cn = min(64, end - base);
        int s = 0;
        float logit = -INFINITY;
        if (lane < cn) {
            s = colb[base + lane];
            float e = as2[s] + adn;
            logit = e > 0.f ? e : 0.2f * e;
        }
        float cmax = logit;
        #pragma unroll
        for (int mk = 32; mk >= 1; mk >>= 1) cmax = fmaxf(cmax, __shfl_xor(cmax, mk, 64));
        float newm = fmaxf(m, cmax);
        float scale = __expf(m - newm);
        acc *= scale; denom *= scale; m = newm;
        float p = (lane < cn) ? __expf(logit - m) : 0.f;
        float psum = p;
        #pragma unroll
        for (int mk = 32; mk >= 1; mk >>= 1) psum += __shfl_xor(psum, mk, 64);
        denom += psum;
        for (int e = 0; e < cn; ++e) {
            float pe = __shfl(p, e, 64);
            int se = __shfl(s, e, 64);
            acc = fmaf(pe, h2[(size_t)se * C2 + lane], acc);
        }
    }
    float v = acc / denom + b2[lane];
    float mx = v;
    #pragma unroll
    for (int mk = 32; mk >= 1; mk >>= 1) mx = fmaxf(mx, __shfl_xor(mx, mk, 64));
    float ex = __expf(v - mx);
    float sum = ex;
    #pragma unroll
    for (int mk = 32; mk >= 1; mk >>= 1) sum += __shfl_xor(sum, mk, 64);
    out[(size_t)n * C2 + lane] = v - mx - logf(sum);
}

extern "C" void kernel_launch(void* const* d_in, const int* in_sizes, int n_in,
                              void* d_out, int out_size, void* d_ws, size_t ws_size,
                              hipStream_t stream) {
    const float* x      = (const float*)d_in[0];
    const int*   ei     = (const int*)d_in[1];
    const float* W1     = (const float*)d_in[2];
    const float* att_s1 = (const float*)d_in[3];
    const float* att_d1 = (const float*)d_in[4];
    const float* b1     = (const float*)d_in[5];
    const float* W2     = (const float*)d_in[6];
    const float* att_s2 = (const float*)d_in[7];
    const float* att_d2 = (const float*)d_in[8];
    const float* b2     = (const float*)d_in[9];
    float* out = (float*)d_out;

    const int N = out_size / C2;          // 50000
    const int E = in_sizes[1] / 2;        // 1.6M
    const int ETOT = E + N;

    char* ws = (char*)d_ws;
    size_t off = 0;
    auto alloc = [&](size_t bytes) -> void* {
        void* p = ws + off;
        off += (bytes + 255) & ~(size_t)255;
        return p;
    };
    float* h1   = (float*)alloc((size_t)N * C1 * 4);   // 51.2 MB (h2 aliases into it later-safe region)
    float* x1e  = (float*)alloc((size_t)N * C1 * 4);   // 51.2 MB
    float* as1  = (float*)alloc((size_t)N * NH * 4);
    float* ad1  = (float*)alloc((size_t)N * NH * 4);
    float* as2  = (float*)alloc((size_t)N * 4);
    float* ad2  = (float*)alloc((size_t)N * 4);
    int*   cnt    = (int*)alloc((size_t)N * 4);
    int*   rowptr = (int*)alloc((size_t)(N + 1) * 4);
    int*   cursor = (int*)alloc((size_t)N * 4);
    int*   colb   = (int*)alloc((size_t)ETOT * 4);
    float* h2 = h1;   // h1 dead after agg1; reuse its space for h2 [N,64]

    // --- CSR build (by dst) ---
    zero_kernel<<<(N + 255) / 256, 256, 0, stream>>>(cnt, N);
    hist_kernel<<<(ETOT + 255) / 256, 256, 0, stream>>>(ei, E, ETOT, cnt);
    scan_kernel<<<1, 1024, 0, stream>>>(cnt, rowptr, cursor, N, ETOT);
    scatter_kernel<<<(ETOT + 255) / 256, 256, 0, stream>>>(ei, E, ETOT, cursor, colb);

    // --- Layer 1 ---
    gemm1_kernel<<<(N + TM1 - 1) / TM1, 256, 0, stream>>>(x, W1, att_s1, att_d1,
                                                          h1, as1, ad1, N);
    agg1_kernel<<<N, 256, 0, stream>>>(rowptr, colb, as1, ad1, h1, b1, x1e, N);

    // --- Layer 2 ---
    gemm2_kernel<<<(N + 15) / 16, 256, 0, stream>>>(x1e, W2, att_s2, att_d2,
                                                    h2, as2, ad2, N);
    agg2_kernel<<<(N + 3) / 4, 256, 0, stream>>>(rowptr, colb, as2, ad2, h2, b2, out, N);
}

// Round 2
// 706.867 us; speedup vs baseline: 1.0299x; 1.0299x over previous
//
#include <hip/hip_runtime.h>
#include <hip/hip_bf16.h>
#include <math.h>

// GAT 2-layer forward for MI355X.
// R2: h1/h2 stored as bf16 to halve the edge-gather traffic (agg1 was
// gather-traffic-bound: 854MB @ 3.6TB/s). Softmax logits/alphas stay fp32.

#define FIN 128
#define C1 256   // H*D layer1
#define NH 8
#define HD 32
#define C2 64    // F_out
#define TM1 16
#define CH1 64

__global__ void zero_kernel(int* p, int n) {
    int i = blockIdx.x * 256 + threadIdx.x;
    if (i < n) p[i] = 0;
}

__global__ void hist_kernel(const int* __restrict__ ei, int E, int ETOT, int* cnt) {
    int e = blockIdx.x * 256 + threadIdx.x;
    if (e >= ETOT) return;
    int dst = (e < E) ? ei[E + e] : (e - E);
    atomicAdd(&cnt[dst], 1);
}

// 1024-thread single-block scan: exclusive prefix over cnt[0..n) -> rowptr, cursor
__global__ void scan_kernel(const int* __restrict__ cnt, int* rowptr, int* cursor,
                            int n, int ETOT) {
    __shared__ int wsum[16];
    __shared__ int carry_s;
    __shared__ int tot_s;
    int tid = threadIdx.x, lane = tid & 63, w = tid >> 6;
    if (tid == 0) carry_s = 0;
    __syncthreads();
    for (int base = 0; base < n; base += 1024) {
        int i = base + tid;
        int v = (i < n) ? cnt[i] : 0;
        int sc = v;
        #pragma unroll
        for (int d = 1; d < 64; d <<= 1) {
            int t = __shfl_up(sc, d, 64);
            if (lane >= d) sc += t;
        }
        if (lane == 63) wsum[w] = sc;
        __syncthreads();
        if (w == 0 && lane < 16) {
            int t = wsum[lane];
            int s2 = t;
            #pragma unroll
            for (int d = 1; d < 16; d <<= 1) {
                int u = __shfl_up(s2, d, 64);
                if (lane >= d) s2 += u;
            }
            if (lane == 15) tot_s = s2;
            wsum[lane] = s2 - t;   // exclusive wave offset
        }
        __syncthreads();
        int excl = carry_s + wsum[w] + (sc - v);
        if (i < n) { rowptr[i] = excl; cursor[i] = excl; }
        __syncthreads();
        if (tid == 0) carry_s += tot_s;
        __syncthreads();
    }
    if (tid == 0) rowptr[n] = ETOT;
}

__global__ void scatter_kernel(const int* __restrict__ ei, int E, int ETOT,
                               int* cursor, int* colb) {
    int e = blockIdx.x * 256 + threadIdx.x;
    if (e >= ETOT) return;
    int src, dst;
    if (e < E) { src = ei[e]; dst = ei[E + e]; }
    else       { src = e - E; dst = e - E; }
    int pos = atomicAdd(&cursor[dst], 1);
    colb[pos] = src;
}

// h1 = x @ W1  [N,256] stored bf16, plus a_s1/a_d1 per (node, head) in f32
__global__ __launch_bounds__(256) void gemm1_kernel(
    const float* __restrict__ x, const float* __restrict__ W1,
    const float* __restrict__ att_s, const float* __restrict__ att_d,
    __hip_bfloat16* __restrict__ h1, float* __restrict__ as1, float* __restrict__ ad1, int N) {
    __shared__ float xs[TM1][FIN];
    int tid = threadIdx.x;
    int row0 = blockIdx.x * TM1;
    #pragma unroll
    for (int i = 0; i < 8; ++i) {
        int f = tid + i * 256;
        int r = f >> 7, k = f & 127;
        int gr = row0 + r;
        xs[r][k] = (gr < N) ? x[(size_t)gr * FIN + k] : 0.f;
    }
    __syncthreads();
    float acc[TM1];
    #pragma unroll
    for (int r = 0; r < TM1; ++r) acc[r] = 0.f;
    const int j = tid;
    for (int k = 0; k < FIN; k += 4) {
        float w0 = W1[(size_t)(k + 0) * C1 + j];
        float w1 = W1[(size_t)(k + 1) * C1 + j];
        float w2 = W1[(size_t)(k + 2) * C1 + j];
        float w3 = W1[(size_t)(k + 3) * C1 + j];
        #pragma unroll
        for (int r = 0; r < TM1; ++r) {
            float4 xv = *reinterpret_cast<const float4*>(&xs[r][k]);
            acc[r] = fmaf(xv.x, w0, acc[r]);
            acc[r] = fmaf(xv.y, w1, acc[r]);
            acc[r] = fmaf(xv.z, w2, acc[r]);
            acc[r] = fmaf(xv.w, w3, acc[r]);
        }
    }
    int hd = j >> 5, d = j & 31;
    float asw = att_s[hd * HD + d], adw = att_d[hd * HD + d];
    #pragma unroll
    for (int r = 0; r < TM1; ++r) {
        int row = row0 + r;
        if (row >= N) break;
        float v = acc[r];
        h1[(size_t)row * C1 + j] = __float2bfloat16(v);
        float ps = v * asw, pd = v * adw;
        #pragma unroll
        for (int m = 16; m >= 1; m >>= 1) {
            ps += __shfl_xor(ps, m, 64);
            pd += __shfl_xor(pd, m, 64);
        }
        if (d == 0) { as1[row * NH + hd] = ps; ad1[row * NH + hd] = pd; }
    }
}

// Layer-1 aggregation: one block per node; online segment softmax + bf16 gather-sum.
__global__ __launch_bounds__(256) void agg1_kernel(
    const int* __restrict__ rowptr, const int* __restrict__ colb,
    const float* __restrict__ as1, const float* __restrict__ ad1,
    const __hip_bfloat16* __restrict__ h1, const float* __restrict__ b1,
    float* __restrict__ x1e, int N) {
    int n = blockIdx.x;
    int tid = threadIdx.x, hd = tid >> 5, d = tid & 31;
    int start = rowptr[n], end = rowptr[n + 1];
    __shared__ float sp[CH1 * 9];      // per-edge per-head logits then p; stride 9
    __shared__ int ssrc[CH1];
    __shared__ float adv[NH];
    if (tid < NH) adv[tid] = ad1[n * NH + tid];
    __syncthreads();
    float advr[NH];
    #pragma unroll
    for (int h = 0; h < NH; ++h) advr[h] = adv[h];

    float m = -INFINITY, denom = 0.f, acc = 0.f;
    for (int base = start; base < end; base += CH1) {
        int cn = min(CH1, end - base);
        if (tid < cn) {
            int s = colb[base + tid];
            ssrc[tid] = s;
            const float4* ap = reinterpret_cast<const float4*>(as1 + (size_t)s * NH);
            float4 a0 = ap[0], a1 = ap[1];
            float av[8] = {a0.x, a0.y, a0.z, a0.w, a1.x, a1.y, a1.z, a1.w};
            #pragma unroll
            for (int h = 0; h < NH; ++h) {
                float e = av[h] + advr[h];
                e = e > 0.f ? e : 0.2f * e;
                sp[tid * 9 + h] = e;
            }
        }
        __syncthreads();
        // per-head chunk max
        float cmax = -INFINITY;
        for (int e = d; e < cn; e += 32) cmax = fmaxf(cmax, sp[e * 9 + hd]);
        #pragma unroll
        for (int mk = 16; mk >= 1; mk >>= 1) cmax = fmaxf(cmax, __shfl_xor(cmax, mk, 64));
        float newm = fmaxf(m, cmax);
        float scale = __expf(m - newm);     // m=-inf -> 0
        acc *= scale; denom *= scale; m = newm;
        // p = exp(logit - m), overwrite in LDS (same 32-lane group, wave-synchronous)
        float psum = 0.f;
        for (int e = d; e < cn; e += 32) {
            float p = __expf(sp[e * 9 + hd] - m);
            sp[e * 9 + hd] = p;
            psum += p;
        }
        #pragma unroll
        for (int mk = 16; mk >= 1; mk >>= 1) psum += __shfl_xor(psum, mk, 64);
        denom += psum;
        // gather-accumulate: 512B bf16 row reads of h1[src]
        float accl = acc;
        #pragma unroll 2
        for (int e = 0; e < cn; ++e) {
            float p = sp[e * 9 + hd];
            float hv = __bfloat162float(h1[(size_t)ssrc[e] * C1 + tid]);
            accl = fmaf(p, hv, accl);
        }
        acc = accl;
        __syncthreads();   // before next chunk overwrites sp/ssrc
    }
    float outv = acc / denom + b1[tid];
    x1e[(size_t)n * C1 + tid] = outv > 0.f ? outv : __expf(outv) - 1.f;
}

// h2 = x1e @ W2 [N,64] stored bf16, plus a_s2/a_d2 (H=1) in f32
__global__ __launch_bounds__(256) void gemm2_kernel(
    const float* __restrict__ x1e, const float* __restrict__ W2,
    const float* __restrict__ att_s2, const float* __restrict__ att_d2,
    __hip_bfloat16* __restrict__ h2, float* __restrict__ as2, float* __restrict__ ad2, int N) {
    __shared__ float xs[16][C1];
    int tid = threadIdx.x;
    int row0 = blockIdx.x * 16;
    #pragma unroll
    for (int i = 0; i < 16; ++i) {
        int f = tid + i * 256;
        int r = f >> 8, k = f & 255;
        int gr = row0 + r;
        xs[r][k] = (gr < N) ? x1e[(size_t)gr * C1 + k] : 0.f;
    }
    __syncthreads();
    int j = tid & 63, rg = tid >> 6;   // wave rg handles rows rg*4..rg*4+3, cols 0..63
    float acc[4] = {0.f, 0.f, 0.f, 0.f};
    for (int k = 0; k < C1; k += 4) {
        float w0 = W2[(size_t)(k + 0) * C2 + j];
        float w1 = W2[(size_t)(k + 1) * C2 + j];
        float w2v = W2[(size_t)(k + 2) * C2 + j];
        float w3 = W2[(size_t)(k + 3) * C2 + j];
        #pragma unroll
        for (int r = 0; r < 4; ++r) {
            float4 xv = *reinterpret_cast<const float4*>(&xs[rg * 4 + r][k]);
            acc[r] = fmaf(xv.x, w0, acc[r]);
            acc[r] = fmaf(xv.y, w1, acc[r]);
            acc[r] = fmaf(xv.z, w2v, acc[r]);
            acc[r] = fmaf(xv.w, w3, acc[r]);
        }
    }
    float asw = att_s2[j], adw = att_d2[j];
    #pragma unroll
    for (int r = 0; r < 4; ++r) {
        int row = row0 + rg * 4 + r;
        if (row >= N) break;
        float v = acc[r];
        h2[(size_t)row * C2 + j] = __float2bfloat16(v);
        float ps = v * asw, pd = v * adw;
        #pragma unroll
        for (int m = 32; m >= 1; m >>= 1) {
            ps += __shfl_xor(ps, m, 64);
            pd += __shfl_xor(pd, m, 64);
        }
        if (j == 0) { as2[row] = ps; ad2[row] = pd; }
    }
}

// Layer-2 aggregation + bias + log_softmax. One 64-lane wave per node.
__global__ __launch_bounds__(256) void agg2_kernel(
    const int* __restrict__ rowptr, const int* __restrict__ colb,
    const float* __restrict__ as2, const float* __restrict__ ad2,
    const __hip_bfloat16* __restrict__ h2, const float* __restrict__ b2,
    float* __restrict__ out, int N) {
    int wid = threadIdx.x >> 6, lane = threadIdx.x & 63;
    int n = blockIdx.x * 4 + wid;
    if (n >= N) return;
    int start = rowptr[n], end = rowptr[n + 1];
    float adn = ad2[n];
    float m = -INFINITY, denom = 0.f, acc = 0.f;
    for (int base = start; base < end; base += 64) {
        int cn = min(64, end - base);
        int s = 0;
        float logit = -INFINITY;
        if (lane < cn) {
            s = colb[base + lane];
            float e = as2[s] + adn;
            logit = e > 0.f ? e : 0.2f * e;
        }
        float cmax = logit;
        #pragma unroll
        for (int mk = 32; mk >= 1; mk >>= 1) cmax = fmaxf(cmax, __shfl_xor(cmax, mk, 64));
        float newm = fmaxf(m, cmax);
        float scale = __expf(m - newm);
        acc *= scale; denom *= scale; m = newm;
        float p = (lane < cn) ? __expf(logit - m) : 0.f;
        float psum = p;
        #pragma unroll
        for (int mk = 32; mk >= 1; mk >>= 1) psum += __shfl_xor(psum, mk, 64);
        denom += psum;
        #pragma unroll 2
        for (int e = 0; e < cn; ++e) {
            float pe = __shfl(p, e, 64);
            int se = __shfl(s, e, 64);
            float hv = __bfloat162float(h2[(size_t)se * C2 + lane]);
            acc = fmaf(pe, hv, acc);
        }
    }
    float v = acc / denom + b2[lane];
    float mx = v;
    #pragma unroll
    for (int mk = 32; mk >= 1; mk >>= 1) mx = fmaxf(mx, __shfl_xor(mx, mk, 64));
    float ex = __expf(v - mx);
    float sum = ex;
    #pragma unroll
    for (int mk = 32; mk >= 1; mk >>= 1) sum += __shfl_xor(sum, mk, 64);
    out[(size_t)n * C2 + lane] = v - mx - logf(sum);
}

extern "C" void kernel_launch(void* const* d_in, const int* in_sizes, int n_in,
                              void* d_out, int out_size, void* d_ws, size_t ws_size,
                              hipStream_t stream) {
    const float* x      = (const float*)d_in[0];
    const int*   ei     = (const int*)d_in[1];
    const float* W1     = (const float*)d_in[2];
    const float* att_s1 = (const float*)d_in[3];
    const float* att_d1 = (const float*)d_in[4];
    const float* b1     = (const float*)d_in[5];
    const float* W2     = (const float*)d_in[6];
    const float* att_s2 = (const float*)d_in[7];
    const float* att_d2 = (const float*)d_in[8];
    const float* b2     = (const float*)d_in[9];
    float* out = (float*)d_out;

    const int N = out_size / C2;          // 50000
    const int E = in_sizes[1] / 2;        // 1.6M
    const int ETOT = E + N;

    char* ws = (char*)d_ws;
    size_t off = 0;
    auto alloc = [&](size_t bytes) -> void* {
        void* p = ws + off;
        off += (bytes + 255) & ~(size_t)255;
        return p;
    };
    __hip_bfloat16* h1 = (__hip_bfloat16*)alloc((size_t)N * C1 * 2);   // 25.6 MB
    float* x1e  = (float*)alloc((size_t)N * C1 * 4);                   // 51.2 MB
    float* as1  = (float*)alloc((size_t)N * NH * 4);
    float* ad1  = (float*)alloc((size_t)N * NH * 4);
    float* as2  = (float*)alloc((size_t)N * 4);
    float* ad2  = (float*)alloc((size_t)N * 4);
    int*   cnt    = (int*)alloc((size_t)N * 4);
    int*   rowptr = (int*)alloc((size_t)(N + 1) * 4);
    int*   cursor = (int*)alloc((size_t)N * 4);
    int*   colb   = (int*)alloc((size_t)ETOT * 4);
    __hip_bfloat16* h2 = h1;   // h1 dead after agg1; reuse for h2 [N,64] bf16

    // --- CSR build (by dst) ---
    zero_kernel<<<(N + 255) / 256, 256, 0, stream>>>(cnt, N);
    hist_kernel<<<(ETOT + 255) / 256, 256, 0, stream>>>(ei, E, ETOT, cnt);
    scan_kernel<<<1, 1024, 0, stream>>>(cnt, rowptr, cursor, N, ETOT);
    scatter_kernel<<<(ETOT + 255) / 256, 256, 0, stream>>>(ei, E, ETOT, cursor, colb);

    // --- Layer 1 ---
    gemm1_kernel<<<(N + TM1 - 1) / TM1, 256, 0, stream>>>(x, W1, att_s1, att_d1,
                                                          h1, as1, ad1, N);
    agg1_kernel<<<N, 256, 0, stream>>>(rowptr, colb, as1, ad1, h1, b1, x1e, N);

    // --- Layer 2 ---
    gemm2_kernel<<<(N + 15) / 16, 256, 0, stream>>>(x1e, W2, att_s2, att_d2,
                                                    h2, as2, ad2, N);
    agg2_kernel<<<(N + 3) / 4, 256, 0, stream>>>(rowptr, colb, as2, ad2, h2, b2, out, N);
}

// Round 3
// 558.384 us; speedup vs baseline: 1.3038x; 1.2659x over previous
//
#include <hip/hip_runtime.h>
#include <hip/hip_bf16.h>
#include <math.h>

// GAT 2-layer forward for MI355X.
// R3: aggregation kernels restructured to 1 wave/node with vectorized bf16
// gathers (uint2/uint row reads). agg1 was issue-bound (scalar ushort loads,
// 4 waves/node redundancy): 6.6M -> 1.65M wave-iterations.

#define FIN 128
#define C1 256   // H*D layer1
#define NH 8
#define HD 32
#define C2 64    // F_out
#define TM1 16
#define CH1 64

__device__ __forceinline__ float blo(unsigned u) { return __uint_as_float(u << 16); }
__device__ __forceinline__ float bhi(unsigned u) { return __uint_as_float(u & 0xffff0000u); }

__global__ void zero_kernel(int* p, int n) {
    int i = blockIdx.x * 256 + threadIdx.x;
    if (i < n) p[i] = 0;
}

__global__ void hist_kernel(const int* __restrict__ ei, int E, int ETOT, int* cnt) {
    int e = blockIdx.x * 256 + threadIdx.x;
    if (e >= ETOT) return;
    int dst = (e < E) ? ei[E + e] : (e - E);
    atomicAdd(&cnt[dst], 1);
}

// 1024-thread single-block scan: exclusive prefix over cnt[0..n) -> rowptr, cursor
__global__ void scan_kernel(const int* __restrict__ cnt, int* rowptr, int* cursor,
                            int n, int ETOT) {
    __shared__ int wsum[16];
    __shared__ int carry_s;
    __shared__ int tot_s;
    int tid = threadIdx.x, lane = tid & 63, w = tid >> 6;
    if (tid == 0) carry_s = 0;
    __syncthreads();
    for (int base = 0; base < n; base += 1024) {
        int i = base + tid;
        int v = (i < n) ? cnt[i] : 0;
        int sc = v;
        #pragma unroll
        for (int d = 1; d < 64; d <<= 1) {
            int t = __shfl_up(sc, d, 64);
            if (lane >= d) sc += t;
        }
        if (lane == 63) wsum[w] = sc;
        __syncthreads();
        if (w == 0 && lane < 16) {
            int t = wsum[lane];
            int s2 = t;
            #pragma unroll
            for (int d = 1; d < 16; d <<= 1) {
                int u = __shfl_up(s2, d, 64);
                if (lane >= d) s2 += u;
            }
            if (lane == 15) tot_s = s2;
            wsum[lane] = s2 - t;   // exclusive wave offset
        }
        __syncthreads();
        int excl = carry_s + wsum[w] + (sc - v);
        if (i < n) { rowptr[i] = excl; cursor[i] = excl; }
        __syncthreads();
        if (tid == 0) carry_s += tot_s;
        __syncthreads();
    }
    if (tid == 0) rowptr[n] = ETOT;
}

__global__ void scatter_kernel(const int* __restrict__ ei, int E, int ETOT,
                               int* cursor, int* colb) {
    int e = blockIdx.x * 256 + threadIdx.x;
    if (e >= ETOT) return;
    int src, dst;
    if (e < E) { src = ei[e]; dst = ei[E + e]; }
    else       { src = e - E; dst = e - E; }
    int pos = atomicAdd(&cursor[dst], 1);
    colb[pos] = src;
}

// h1 = x @ W1  [N,256] stored bf16, plus a_s1/a_d1 per (node, head) in f32
__global__ __launch_bounds__(256) void gemm1_kernel(
    const float* __restrict__ x, const float* __restrict__ W1,
    const float* __restrict__ att_s, const float* __restrict__ att_d,
    __hip_bfloat16* __restrict__ h1, float* __restrict__ as1, float* __restrict__ ad1, int N) {
    __shared__ float xs[TM1][FIN];
    int tid = threadIdx.x;
    int row0 = blockIdx.x * TM1;
    #pragma unroll
    for (int i = 0; i < 8; ++i) {
        int f = tid + i * 256;
        int r = f >> 7, k = f & 127;
        int gr = row0 + r;
        xs[r][k] = (gr < N) ? x[(size_t)gr * FIN + k] : 0.f;
    }
    __syncthreads();
    float acc[TM1];
    #pragma unroll
    for (int r = 0; r < TM1; ++r) acc[r] = 0.f;
    const int j = tid;
    for (int k = 0; k < FIN; k += 4) {
        float w0 = W1[(size_t)(k + 0) * C1 + j];
        float w1 = W1[(size_t)(k + 1) * C1 + j];
        float w2 = W1[(size_t)(k + 2) * C1 + j];
        float w3 = W1[(size_t)(k + 3) * C1 + j];
        #pragma unroll
        for (int r = 0; r < TM1; ++r) {
            float4 xv = *reinterpret_cast<const float4*>(&xs[r][k]);
            acc[r] = fmaf(xv.x, w0, acc[r]);
            acc[r] = fmaf(xv.y, w1, acc[r]);
            acc[r] = fmaf(xv.z, w2, acc[r]);
            acc[r] = fmaf(xv.w, w3, acc[r]);
        }
    }
    int hd = j >> 5, d = j & 31;
    float asw = att_s[hd * HD + d], adw = att_d[hd * HD + d];
    #pragma unroll
    for (int r = 0; r < TM1; ++r) {
        int row = row0 + r;
        if (row >= N) break;
        float v = acc[r];
        h1[(size_t)row * C1 + j] = __float2bfloat16(v);
        float ps = v * asw, pd = v * adw;
        #pragma unroll
        for (int m = 16; m >= 1; m >>= 1) {
            ps += __shfl_xor(ps, m, 64);
            pd += __shfl_xor(pd, m, 64);
        }
        if (d == 0) { as1[row * NH + hd] = ps; ad1[row * NH + hd] = pd; }
    }
}

// Layer-1 aggregation: ONE WAVE per node; 4 bf16 dims per lane (8B row loads).
// Head h = lane>>3; per-head softmax via 8-lane shfl_xor groups. No barriers.
__global__ __launch_bounds__(256) void agg1_kernel(
    const int* __restrict__ rowptr, const int* __restrict__ colb,
    const float* __restrict__ as1, const float* __restrict__ ad1,
    const __hip_bfloat16* __restrict__ h1, const float* __restrict__ b1,
    float* __restrict__ x1e, int N) {
    int wid = threadIdx.x >> 6, lane = threadIdx.x & 63;
    int n = blockIdx.x * 4 + wid;
    __shared__ float sp[4][CH1 * 9];   // per-wave: per-edge per-head logits->p
    __shared__ int ssrc[4][CH1];
    __shared__ float advs[4][NH];
    if (n >= N) return;                // wave-level only, no block barriers below
    int start = rowptr[n], end = rowptr[n + 1];
    int h = lane >> 3;                 // head owned by this lane
    int sub = lane & 7;
    if (lane < NH) advs[wid][lane] = ad1[n * NH + lane];
    float adr[NH];
    #pragma unroll
    for (int hh = 0; hh < NH; ++hh) adr[hh] = advs[wid][hh];

    float m = -INFINITY, denom = 0.f;
    float acc0 = 0.f, acc1 = 0.f, acc2 = 0.f, acc3 = 0.f;
    for (int base = start; base < end; base += CH1) {
        int cn = min(CH1, end - base);
        if (lane < cn) {
            int s = colb[base + lane];
            ssrc[wid][lane] = s;
            const float4* ap = reinterpret_cast<const float4*>(as1 + (size_t)s * NH);
            float4 a0 = ap[0], a1 = ap[1];
            float av[8] = {a0.x, a0.y, a0.z, a0.w, a1.x, a1.y, a1.z, a1.w};
            #pragma unroll
            for (int hh = 0; hh < NH; ++hh) {
                float e = av[hh] + adr[hh];
                e = e > 0.f ? e : 0.2f * e;
                sp[wid][lane * 9 + hh] = e;
            }
        }
        // per-head chunk max (8-lane groups)
        float cmax = -INFINITY;
        for (int e = sub; e < cn; e += 8) cmax = fmaxf(cmax, sp[wid][e * 9 + h]);
        #pragma unroll
        for (int mk = 4; mk >= 1; mk >>= 1) cmax = fmaxf(cmax, __shfl_xor(cmax, mk, 64));
        float newm = fmaxf(m, cmax);
        float scale = __expf(m - newm);     // m=-inf -> 0
        acc0 *= scale; acc1 *= scale; acc2 *= scale; acc3 *= scale;
        denom *= scale; m = newm;
        float psum = 0.f;
        for (int e = sub; e < cn; e += 8) {
            float p = __expf(sp[wid][e * 9 + h] - m);
            sp[wid][e * 9 + h] = p;
            psum += p;
        }
        #pragma unroll
        for (int mk = 4; mk >= 1; mk >>= 1) psum += __shfl_xor(psum, mk, 64);
        denom += psum;
        // gather: full 512B row per wave-instruction (8B/lane)
        #pragma unroll 4
        for (int e = 0; e < cn; ++e) {
            float p = sp[wid][e * 9 + h];
            int s = ssrc[wid][e];
            uint2 u = *reinterpret_cast<const uint2*>(h1 + (size_t)s * C1 + lane * 4);
            acc0 = fmaf(p, blo(u.x), acc0);
            acc1 = fmaf(p, bhi(u.x), acc1);
            acc2 = fmaf(p, blo(u.y), acc2);
            acc3 = fmaf(p, bhi(u.y), acc3);
        }
    }
    float invd = 1.f / denom;
    float4 bv = *reinterpret_cast<const float4*>(b1 + lane * 4);
    float v0 = acc0 * invd + bv.x;
    float v1 = acc1 * invd + bv.y;
    float v2 = acc2 * invd + bv.z;
    float v3 = acc3 * invd + bv.w;
    float4 ov;
    ov.x = v0 > 0.f ? v0 : __expf(v0) - 1.f;
    ov.y = v1 > 0.f ? v1 : __expf(v1) - 1.f;
    ov.z = v2 > 0.f ? v2 : __expf(v2) - 1.f;
    ov.w = v3 > 0.f ? v3 : __expf(v3) - 1.f;
    *reinterpret_cast<float4*>(x1e + (size_t)n * C1 + lane * 4) = ov;
}

// h2 = x1e @ W2 [N,64] stored bf16, plus a_s2/a_d2 (H=1) in f32
__global__ __launch_bounds__(256) void gemm2_kernel(
    const float* __restrict__ x1e, const float* __restrict__ W2,
    const float* __restrict__ att_s2, const float* __restrict__ att_d2,
    __hip_bfloat16* __restrict__ h2, float* __restrict__ as2, float* __restrict__ ad2, int N) {
    __shared__ float xs[16][C1];
    int tid = threadIdx.x;
    int row0 = blockIdx.x * 16;
    #pragma unroll
    for (int i = 0; i < 16; ++i) {
        int f = tid + i * 256;
        int r = f >> 8, k = f & 255;
        int gr = row0 + r;
        xs[r][k] = (gr < N) ? x1e[(size_t)gr * C1 + k] : 0.f;
    }
    __syncthreads();
    int j = tid & 63, rg = tid >> 6;   // wave rg handles rows rg*4..rg*4+3, cols 0..63
    float acc[4] = {0.f, 0.f, 0.f, 0.f};
    for (int k = 0; k < C1; k += 4) {
        float w0 = W2[(size_t)(k + 0) * C2 + j];
        float w1 = W2[(size_t)(k + 1) * C2 + j];
        float w2v = W2[(size_t)(k + 2) * C2 + j];
        float w3 = W2[(size_t)(k + 3) * C2 + j];
        #pragma unroll
        for (int r = 0; r < 4; ++r) {
            float4 xv = *reinterpret_cast<const float4*>(&xs[rg * 4 + r][k]);
            acc[r] = fmaf(xv.x, w0, acc[r]);
            acc[r] = fmaf(xv.y, w1, acc[r]);
            acc[r] = fmaf(xv.z, w2v, acc[r]);
            acc[r] = fmaf(xv.w, w3, acc[r]);
        }
    }
    float asw = att_s2[j], adw = att_d2[j];
    #pragma unroll
    for (int r = 0; r < 4; ++r) {
        int row = row0 + rg * 4 + r;
        if (row >= N) break;
        float v = acc[r];
        h2[(size_t)row * C2 + j] = __float2bfloat16(v);
        float ps = v * asw, pd = v * adw;
        #pragma unroll
        for (int m = 32; m >= 1; m >>= 1) {
            ps += __shfl_xor(ps, m, 64);
            pd += __shfl_xor(pd, m, 64);
        }
        if (j == 0) { as2[row] = ps; ad2[row] = pd; }
    }
}

// Layer-2 aggregation + bias + log_softmax. One wave per node, parity-split:
// lanes 0-31 even edges, 32-63 odd edges; 2 dims/lane (4B loads); combine at end.
__global__ __launch_bounds__(256) void agg2_kernel(
    const int* __restrict__ rowptr, const int* __restrict__ colb,
    const float* __restrict__ as2, const float* __restrict__ ad2,
    const __hip_bfloat16* __restrict__ h2, const float* __restrict__ b2,
    float* __restrict__ out, int N) {
    int wid = threadIdx.x >> 6, lane = threadIdx.x & 63;
    int n = blockIdx.x * 4 + wid;
    __shared__ float sp2[4][64];
    __shared__ int ssrc2[4][64];
    if (n >= N) return;                // wave-level only
    int start = rowptr[n], end = rowptr[n + 1];
    int eoff = lane >> 5, jj = lane & 31;   // parity, dim pair index
    float adn = ad2[n];
    float m = -INFINITY, denom = 0.f;
    float acc0 = 0.f, acc1 = 0.f;
    for (int base = start; base < end; base += 64) {
        int cn = min(64, end - base);
        float logit = -INFINITY;
        if (lane < cn) {
            int s = colb[base + lane];
            ssrc2[wid][lane] = s;
            float e = as2[s] + adn;
            logit = e > 0.f ? e : 0.2f * e;
        }
        float cmax = logit;
        #pragma unroll
        for (int mk = 32; mk >= 1; mk >>= 1) cmax = fmaxf(cmax, __shfl_xor(cmax, mk, 64));
        float newm = fmaxf(m, cmax);
        float scale = __expf(m - newm);
        acc0 *= scale; acc1 *= scale; denom *= scale; m = newm;
        float p = (lane < cn) ? __expf(logit - m) : 0.f;
        sp2[wid][lane] = p;
        float psum = p;
        #pragma unroll
        for (int mk = 32; mk >= 1; mk >>= 1) psum += __shfl_xor(psum, mk, 64);
        denom += psum;
        #pragma unroll 4
        for (int e = eoff; e < cn; e += 2) {
            float pe = sp2[wid][e];
            int s = ssrc2[wid][e];
            unsigned u = *reinterpret_cast<const unsigned*>(h2 + (size_t)s * C2 + jj * 2);
            acc0 = fmaf(pe, blo(u), acc0);
            acc1 = fmaf(pe, bhi(u), acc1);
        }
    }
    // combine parity halves (lane <-> lane^32)
    acc0 += __shfl_xor(acc0, 32, 64);
    acc1 += __shfl_xor(acc1, 32, 64);
    float invd = 1.f / denom;
    float v0 = acc0 * invd + b2[jj * 2];
    float v1 = acc1 * invd + b2[jj * 2 + 1];
    // log_softmax over 64 dims (2/lane across 32-lane halves; halves duplicated)
    float mx = fmaxf(v0, v1);
    #pragma unroll
    for (int mk = 16; mk >= 1; mk >>= 1) mx = fmaxf(mx, __shfl_xor(mx, mk, 64));
    float sum = __expf(v0 - mx) + __expf(v1 - mx);
    #pragma unroll
    for (int mk = 16; mk >= 1; mk >>= 1) sum += __shfl_xor(sum, mk, 64);
    float ls = logf(sum);
    if (eoff == 0) {
        float2 o = make_float2(v0 - mx - ls, v1 - mx - ls);
        *reinterpret_cast<float2*>(out + (size_t)n * C2 + jj * 2) = o;
    }
}

extern "C" void kernel_launch(void* const* d_in, const int* in_sizes, int n_in,
                              void* d_out, int out_size, void* d_ws, size_t ws_size,
                              hipStream_t stream) {
    const float* x      = (const float*)d_in[0];
    const int*   ei     = (const int*)d_in[1];
    const float* W1     = (const float*)d_in[2];
    const float* att_s1 = (const float*)d_in[3];
    const float* att_d1 = (const float*)d_in[4];
    const float* b1     = (const float*)d_in[5];
    const float* W2     = (const float*)d_in[6];
    const float* att_s2 = (const float*)d_in[7];
    const float* att_d2 = (const float*)d_in[8];
    const float* b2     = (const float*)d_in[9];
    float* out = (float*)d_out;

    const int N = out_size / C2;          // 50000
    const int E = in_sizes[1] / 2;        // 1.6M
    const int ETOT = E + N;

    char* ws = (char*)d_ws;
    size_t off = 0;
    auto alloc = [&](size_t bytes) -> void* {
        void* p = ws + off;
        off += (bytes + 255) & ~(size_t)255;
        return p;
    };
    __hip_bfloat16* h1 = (__hip_bfloat16*)alloc((size_t)N * C1 * 2);   // 25.6 MB
    float* x1e  = (float*)alloc((size_t)N * C1 * 4);                   // 51.2 MB
    float* as1  = (float*)alloc((size_t)N * NH * 4);
    float* ad1  = (float*)alloc((size_t)N * NH * 4);
    float* as2  = (float*)alloc((size_t)N * 4);
    float* ad2  = (float*)alloc((size_t)N * 4);
    int*   cnt    = (int*)alloc((size_t)N * 4);
    int*   rowptr = (int*)alloc((size_t)(N + 1) * 4);
    int*   cursor = (int*)alloc((size_t)N * 4);
    int*   colb   = (int*)alloc((size_t)ETOT * 4);
    __hip_bfloat16* h2 = h1;   // h1 dead after agg1; reuse for h2 [N,64] bf16

    // --- CSR build (by dst) ---
    zero_kernel<<<(N + 255) / 256, 256, 0, stream>>>(cnt, N);
    hist_kernel<<<(ETOT + 255) / 256, 256, 0, stream>>>(ei, E, ETOT, cnt);
    scan_kernel<<<1, 1024, 0, stream>>>(cnt, rowptr, cursor, N, ETOT);
    scatter_kernel<<<(ETOT + 255) / 256, 256, 0, stream>>>(ei, E, ETOT, cursor, colb);

    // --- Layer 1 ---
    gemm1_kernel<<<(N + TM1 - 1) / TM1, 256, 0, stream>>>(x, W1, att_s1, att_d1,
                                                          h1, as1, ad1, N);
    agg1_kernel<<<(N + 3) / 4, 256, 0, stream>>>(rowptr, colb, as1, ad1, h1, b1, x1e, N);

    // --- Layer 2 ---
    gemm2_kernel<<<(N + 15) / 16, 256, 0, stream>>>(x1e, W2, att_s2, att_d2,
                                                    h2, as2, ad2, N);
    agg2_kernel<<<(N + 3) / 4, 256, 0, stream>>>(rowptr, colb, as2, ad2, h2, b2, out, N);
}

// Round 5
// 404.701 us; speedup vs baseline: 1.7989x; 1.3797x over previous
//
#include <hip/hip_runtime.h>
#include <hip/hip_bf16.h>
#include <math.h>

// GAT 2-layer forward for MI355X.
// R5 = R4 + fix: 4-edges/thread striding had duplicate coverage when the
// thread count exceeded the stride period T (threads base>=T re-processed
// edges also covered at i=1) -> inflated cnt -> OOB colb writes -> crash.
// Guard: base < T in hist and scatter.

#define FIN 128
#define C1 256   // H*D layer1
#define NH 8
#define HD 32
#define C2 64    // F_out
#define TM1 16
#define CH1 64

__device__ __forceinline__ float blo(unsigned u) { return __uint_as_float(u << 16); }
__device__ __forceinline__ float bhi(unsigned u) { return __uint_as_float(u & 0xffff0000u); }

__global__ void zero_kernel(int* p, int n) {
    int i = blockIdx.x * 256 + threadIdx.x;
    if (i < n) p[i] = 0;
}

// 4 edges/thread: count in-degree AND record each edge's rank within its dst.
__global__ void hist_kernel(const int* __restrict__ ei, int E, int ETOT, int T,
                            int* cnt, int* __restrict__ offs) {
    int base = blockIdx.x * 256 + threadIdx.x;
    if (base >= T) return;              // stride period is T: no duplicates
    int d[4], idx[4], o[4];
    #pragma unroll
    for (int i = 0; i < 4; ++i) {
        int e = base + i * T;
        idx[i] = e;
        d[i] = (e < ETOT) ? ((e < E) ? ei[E + e] : (e - E)) : -1;
    }
    #pragma unroll
    for (int i = 0; i < 4; ++i)
        if (d[i] >= 0) o[i] = atomicAdd(&cnt[d[i]], 1);
    #pragma unroll
    for (int i = 0; i < 4; ++i)
        if (d[i] >= 0) offs[idx[i]] = o[i];
}

// Two-level exclusive scan over cnt[0..n).
__global__ void scan1_kernel(const int* __restrict__ cnt, int n,
                             int* __restrict__ pref, int* __restrict__ bsum) {
    int tid = threadIdx.x, lane = tid & 63, w = tid >> 6;
    int i = blockIdx.x * 256 + tid;
    int v = (i < n) ? cnt[i] : 0;
    int sc = v;
    #pragma unroll
    for (int d = 1; d < 64; d <<= 1) {
        int t = __shfl_up(sc, d, 64);
        if (lane >= d) sc += t;
    }
    __shared__ int ws[4];
    if (lane == 63) ws[w] = sc;
    __syncthreads();
    int woff = 0;
    #pragma unroll
    for (int k = 0; k < 4; ++k) woff += (k < w) ? ws[k] : 0;
    if (i < n) pref[i] = woff + sc - v;
    if (tid == 255) bsum[blockIdx.x] = woff + sc;
}

__global__ void scan2_kernel(int* bsum, int nb) {
    int tid = threadIdx.x, lane = tid & 63, w = tid >> 6;
    int v = (tid < nb) ? bsum[tid] : 0;
    int sc = v;
    #pragma unroll
    for (int d = 1; d < 64; d <<= 1) {
        int t = __shfl_up(sc, d, 64);
        if (lane >= d) sc += t;
    }
    __shared__ int ws[4];
    if (lane == 63) ws[w] = sc;
    __syncthreads();
    int woff = 0;
    #pragma unroll
    for (int k = 0; k < 4; ++k) woff += (k < w) ? ws[k] : 0;
    __syncthreads();
    if (tid < nb) bsum[tid] = woff + sc - v;
}

__global__ void scan3_kernel(const int* __restrict__ pref, const int* __restrict__ bsum,
                             int n, int ETOT, int* __restrict__ rowptr) {
    int i = blockIdx.x * 256 + threadIdx.x;
    if (i < n) rowptr[i] = pref[i] + bsum[blockIdx.x];
    if (i == 0) rowptr[n] = ETOT;
}

// No atomics: pos = rowptr[dst] + offs[e]. 4 edges/thread.
__global__ void scatter_kernel(const int* __restrict__ ei, const int* __restrict__ rowptr,
                               const int* __restrict__ offs, int E, int ETOT, int T,
                               int* __restrict__ colb) {
    int base = blockIdx.x * 256 + threadIdx.x;
    if (base >= T) return;              // stride period is T: no duplicates
    #pragma unroll
    for (int i = 0; i < 4; ++i) {
        int e = base + i * T;
        if (e >= ETOT) continue;
        int src, dst;
        if (e < E) { src = ei[e]; dst = ei[E + e]; }
        else       { src = e - E; dst = e - E; }
        colb[rowptr[dst] + offs[e]] = src;
    }
}

// h1 = x @ W1  [N,256] stored bf16, plus a_s1/a_d1 per (node, head) in f32
__global__ __launch_bounds__(256) void gemm1_kernel(
    const float* __restrict__ x, const float* __restrict__ W1,
    const float* __restrict__ att_s, const float* __restrict__ att_d,
    __hip_bfloat16* __restrict__ h1, float* __restrict__ as1, float* __restrict__ ad1, int N) {
    __shared__ float xs[TM1][FIN];
    int tid = threadIdx.x;
    int row0 = blockIdx.x * TM1;
    #pragma unroll
    for (int i = 0; i < 8; ++i) {
        int f = tid + i * 256;
        int r = f >> 7, k = f & 127;
        int gr = row0 + r;
        xs[r][k] = (gr < N) ? x[(size_t)gr * FIN + k] : 0.f;
    }
    __syncthreads();
    float acc[TM1];
    #pragma unroll
    for (int r = 0; r < TM1; ++r) acc[r] = 0.f;
    const int j = tid;
    for (int k = 0; k < FIN; k += 4) {
        float w0 = W1[(size_t)(k + 0) * C1 + j];
        float w1 = W1[(size_t)(k + 1) * C1 + j];
        float w2 = W1[(size_t)(k + 2) * C1 + j];
        float w3 = W1[(size_t)(k + 3) * C1 + j];
        #pragma unroll
        for (int r = 0; r < TM1; ++r) {
            float4 xv = *reinterpret_cast<const float4*>(&xs[r][k]);
            acc[r] = fmaf(xv.x, w0, acc[r]);
            acc[r] = fmaf(xv.y, w1, acc[r]);
            acc[r] = fmaf(xv.z, w2, acc[r]);
            acc[r] = fmaf(xv.w, w3, acc[r]);
        }
    }
    int hd = j >> 5, d = j & 31;
    float asw = att_s[hd * HD + d], adw = att_d[hd * HD + d];
    #pragma unroll
    for (int r = 0; r < TM1; ++r) {
        int row = row0 + r;
        if (row >= N) break;
        float v = acc[r];
        h1[(size_t)row * C1 + j] = __float2bfloat16(v);
        float ps = v * asw, pd = v * adw;
        #pragma unroll
        for (int m = 16; m >= 1; m >>= 1) {
            ps += __shfl_xor(ps, m, 64);
            pd += __shfl_xor(pd, m, 64);
        }
        if (d == 0) { as1[row * NH + hd] = ps; ad1[row * NH + hd] = pd; }
    }
}

// Layer-1 aggregation: ONE WAVE per node; 4 bf16 dims per lane (8B row loads).
__global__ __launch_bounds__(256) void agg1_kernel(
    const int* __restrict__ rowptr, const int* __restrict__ colb,
    const float* __restrict__ as1, const float* __restrict__ ad1,
    const __hip_bfloat16* __restrict__ h1, const float* __restrict__ b1,
    float* __restrict__ x1e, int N) {
    int wid = threadIdx.x >> 6, lane = threadIdx.x & 63;
    int n = blockIdx.x * 4 + wid;
    __shared__ float sp[4][CH1 * 9];
    __shared__ int ssrc[4][CH1];
    __shared__ float advs[4][NH];
    if (n >= N) return;
    int start = rowptr[n], end = rowptr[n + 1];
    int h = lane >> 3;
    int sub = lane & 7;
    if (lane < NH) advs[wid][lane] = ad1[n * NH + lane];
    float adr[NH];
    #pragma unroll
    for (int hh = 0; hh < NH; ++hh) adr[hh] = advs[wid][hh];

    float m = -INFINITY, denom = 0.f;
    float acc0 = 0.f, acc1 = 0.f, acc2 = 0.f, acc3 = 0.f;
    for (int base = start; base < end; base += CH1) {
        int cn = min(CH1, end - base);
        if (lane < cn) {
            int s = colb[base + lane];
            ssrc[wid][lane] = s;
            const float4* ap = reinterpret_cast<const float4*>(as1 + (size_t)s * NH);
            float4 a0 = ap[0], a1 = ap[1];
            float av[8] = {a0.x, a0.y, a0.z, a0.w, a1.x, a1.y, a1.z, a1.w};
            #pragma unroll
            for (int hh = 0; hh < NH; ++hh) {
                float e = av[hh] + adr[hh];
                e = e > 0.f ? e : 0.2f * e;
                sp[wid][lane * 9 + hh] = e;
            }
        }
        float cmax = -INFINITY;
        for (int e = sub; e < cn; e += 8) cmax = fmaxf(cmax, sp[wid][e * 9 + h]);
        #pragma unroll
        for (int mk = 4; mk >= 1; mk >>= 1) cmax = fmaxf(cmax, __shfl_xor(cmax, mk, 64));
        float newm = fmaxf(m, cmax);
        float scale = __expf(m - newm);
        acc0 *= scale; acc1 *= scale; acc2 *= scale; acc3 *= scale;
        denom *= scale; m = newm;
        float psum = 0.f;
        for (int e = sub; e < cn; e += 8) {
            float p = __expf(sp[wid][e * 9 + h] - m);
            sp[wid][e * 9 + h] = p;
            psum += p;
        }
        #pragma unroll
        for (int mk = 4; mk >= 1; mk >>= 1) psum += __shfl_xor(psum, mk, 64);
        denom += psum;
        #pragma unroll 4
        for (int e = 0; e < cn; ++e) {
            float p = sp[wid][e * 9 + h];
            int s = ssrc[wid][e];
            uint2 u = *reinterpret_cast<const uint2*>(h1 + (size_t)s * C1 + lane * 4);
            acc0 = fmaf(p, blo(u.x), acc0);
            acc1 = fmaf(p, bhi(u.x), acc1);
            acc2 = fmaf(p, blo(u.y), acc2);
            acc3 = fmaf(p, bhi(u.y), acc3);
        }
    }
    float invd = 1.f / denom;
    float4 bv = *reinterpret_cast<const float4*>(b1 + lane * 4);
    float v0 = acc0 * invd + bv.x;
    float v1 = acc1 * invd + bv.y;
    float v2 = acc2 * invd + bv.z;
    float v3 = acc3 * invd + bv.w;
    float4 ov;
    ov.x = v0 > 0.f ? v0 : __expf(v0) - 1.f;
    ov.y = v1 > 0.f ? v1 : __expf(v1) - 1.f;
    ov.z = v2 > 0.f ? v2 : __expf(v2) - 1.f;
    ov.w = v3 > 0.f ? v3 : __expf(v3) - 1.f;
    *reinterpret_cast<float4*>(x1e + (size_t)n * C1 + lane * 4) = ov;
}

// h2 = x1e @ W2 [N,64] stored bf16, plus a_s2/a_d2 (H=1) in f32
__global__ __launch_bounds__(256) void gemm2_kernel(
    const float* __restrict__ x1e, const float* __restrict__ W2,
    const float* __restrict__ att_s2, const float* __restrict__ att_d2,
    __hip_bfloat16* __restrict__ h2, float* __restrict__ as2, float* __restrict__ ad2, int N) {
    __shared__ float xs[16][C1];
    int tid = threadIdx.x;
    int row0 = blockIdx.x * 16;
    #pragma unroll
    for (int i = 0; i < 16; ++i) {
        int f = tid + i * 256;
        int r = f >> 8, k = f & 255;
        int gr = row0 + r;
        xs[r][k] = (gr < N) ? x1e[(size_t)gr * C1 + k] : 0.f;
    }
    __syncthreads();
    int j = tid & 63, rg = tid >> 6;
    float acc[4] = {0.f, 0.f, 0.f, 0.f};
    for (int k = 0; k < C1; k += 4) {
        float w0 = W2[(size_t)(k + 0) * C2 + j];
        float w1 = W2[(size_t)(k + 1) * C2 + j];
        float w2v = W2[(size_t)(k + 2) * C2 + j];
        float w3 = W2[(size_t)(k + 3) * C2 + j];
        #pragma unroll
        for (int r = 0; r < 4; ++r) {
            float4 xv = *reinterpret_cast<const float4*>(&xs[rg * 4 + r][k]);
            acc[r] = fmaf(xv.x, w0, acc[r]);
            acc[r] = fmaf(xv.y, w1, acc[r]);
            acc[r] = fmaf(xv.z, w2v, acc[r]);
            acc[r] = fmaf(xv.w, w3, acc[r]);
        }
    }
    float asw = att_s2[j], adw = att_d2[j];
    #pragma unroll
    for (int r = 0; r < 4; ++r) {
        int row = row0 + rg * 4 + r;
        if (row >= N) break;
        float v = acc[r];
        h2[(size_t)row * C2 + j] = __float2bfloat16(v);
        float ps = v * asw, pd = v * adw;
        #pragma unroll
        for (int m = 32; m >= 1; m >>= 1) {
            ps += __shfl_xor(ps, m, 64);
            pd += __shfl_xor(pd, m, 64);
        }
        if (j == 0) { as2[row] = ps; ad2[row] = pd; }
    }
}

// Layer-2 aggregation + bias + log_softmax. One wave per node, parity-split.
__global__ __launch_bounds__(256) void agg2_kernel(
    const int* __restrict__ rowptr, const int* __restrict__ colb,
    const float* __restrict__ as2, const float* __restrict__ ad2,
    const __hip_bfloat16* __restrict__ h2, const float* __restrict__ b2,
    float* __restrict__ out, int N) {
    int wid = threadIdx.x >> 6, lane = threadIdx.x & 63;
    int n = blockIdx.x * 4 + wid;
    __shared__ float sp2[4][64];
    __shared__ int ssrc2[4][64];
    if (n >= N) return;
    int start = rowptr[n], end = rowptr[n + 1];
    int eoff = lane >> 5, jj = lane & 31;
    float adn = ad2[n];
    float m = -INFINITY, denom = 0.f;
    float acc0 = 0.f, acc1 = 0.f;
    for (int base = start; base < end; base += 64) {
        int cn = min(64, end - base);
        float logit = -INFINITY;
        if (lane < cn) {
            int s = colb[base + lane];
            ssrc2[wid][lane] = s;
            float e = as2[s] + adn;
            logit = e > 0.f ? e : 0.2f * e;
        }
        float cmax = logit;
        #pragma unroll
        for (int mk = 32; mk >= 1; mk >>= 1) cmax = fmaxf(cmax, __shfl_xor(cmax, mk, 64));
        float newm = fmaxf(m, cmax);
        float scale = __expf(m - newm);
        acc0 *= scale; acc1 *= scale; denom *= scale; m = newm;
        float p = (lane < cn) ? __expf(logit - m) : 0.f;
        sp2[wid][lane] = p;
        float psum = p;
        #pragma unroll
        for (int mk = 32; mk >= 1; mk >>= 1) psum += __shfl_xor(psum, mk, 64);
        denom += psum;
        #pragma unroll 4
        for (int e = eoff; e < cn; e += 2) {
            float pe = sp2[wid][e];
            int s = ssrc2[wid][e];
            unsigned u = *reinterpret_cast<const unsigned*>(h2 + (size_t)s * C2 + jj * 2);
            acc0 = fmaf(pe, blo(u), acc0);
            acc1 = fmaf(pe, bhi(u), acc1);
        }
    }
    acc0 += __shfl_xor(acc0, 32, 64);
    acc1 += __shfl_xor(acc1, 32, 64);
    float invd = 1.f / denom;
    float v0 = acc0 * invd + b2[jj * 2];
    float v1 = acc1 * invd + b2[jj * 2 + 1];
    float mx = fmaxf(v0, v1);
    #pragma unroll
    for (int mk = 16; mk >= 1; mk >>= 1) mx = fmaxf(mx, __shfl_xor(mx, mk, 64));
    float sum = __expf(v0 - mx) + __expf(v1 - mx);
    #pragma unroll
    for (int mk = 16; mk >= 1; mk >>= 1) sum += __shfl_xor(sum, mk, 64);
    float ls = logf(sum);
    if (eoff == 0) {
        float2 o = make_float2(v0 - mx - ls, v1 - mx - ls);
        *reinterpret_cast<float2*>(out + (size_t)n * C2 + jj * 2) = o;
    }
}

extern "C" void kernel_launch(void* const* d_in, const int* in_sizes, int n_in,
                              void* d_out, int out_size, void* d_ws, size_t ws_size,
                              hipStream_t stream) {
    const float* x      = (const float*)d_in[0];
    const int*   ei     = (const int*)d_in[1];
    const float* W1     = (const float*)d_in[2];
    const float* att_s1 = (const float*)d_in[3];
    const float* att_d1 = (const float*)d_in[4];
    const float* b1     = (const float*)d_in[5];
    const float* W2     = (const float*)d_in[6];
    const float* att_s2 = (const float*)d_in[7];
    const float* att_d2 = (const float*)d_in[8];
    const float* b2     = (const float*)d_in[9];
    float* out = (float*)d_out;

    const int N = out_size / C2;          // 50000
    const int E = in_sizes[1] / 2;        // 1.6M
    const int ETOT = E + N;
    const int NB = (N + 255) / 256;       // scan blocks

    char* ws = (char*)d_ws;
    size_t off = 0;
    auto alloc = [&](size_t bytes) -> void* {
        void* p = ws + off;
        off += (bytes + 255) & ~(size_t)255;
        return p;
    };
    __hip_bfloat16* h1 = (__hip_bfloat16*)alloc((size_t)N * C1 * 2);   // 25.6 MB
    float* x1e  = (float*)alloc((size_t)N * C1 * 4);                   // 51.2 MB
    float* as1  = (float*)alloc((size_t)N * NH * 4);
    float* ad1  = (float*)alloc((size_t)N * NH * 4);
    float* as2  = (float*)alloc((size_t)N * 4);
    float* ad2  = (float*)alloc((size_t)N * 4);
    int*   cnt    = (int*)alloc((size_t)N * 4);
    int*   rowptr = (int*)alloc((size_t)(N + 1) * 4);
    int*   pref   = (int*)alloc((size_t)N * 4);
    int*   bsum   = (int*)alloc((size_t)NB * 4);
    int*   offs   = (int*)alloc((size_t)ETOT * 4);   // 6.6 MB
    int*   colb   = (int*)alloc((size_t)ETOT * 4);   // 6.6 MB
    __hip_bfloat16* h2 = h1;   // h1 dead after agg1; reuse for h2 [N,64] bf16

    // --- CSR build (by dst), atomic-rank + two-level scan, no scatter atomics ---
    const int T = (ETOT + 3) / 4;   // edges per stride
    zero_kernel<<<(N + 255) / 256, 256, 0, stream>>>(cnt, N);
    hist_kernel<<<(T + 255) / 256, 256, 0, stream>>>(ei, E, ETOT, T, cnt, offs);
    scan1_kernel<<<NB, 256, 0, stream>>>(cnt, N, pref, bsum);
    scan2_kernel<<<1, 256, 0, stream>>>(bsum, NB);
    scan3_kernel<<<NB, 256, 0, stream>>>(pref, bsum, N, ETOT, rowptr);
    scatter_kernel<<<(T + 255) / 256, 256, 0, stream>>>(ei, rowptr, offs, E, ETOT, T, colb);

    // --- Layer 1 ---
    gemm1_kernel<<<(N + TM1 - 1) / TM1, 256, 0, stream>>>(x, W1, att_s1, att_d1,
                                                          h1, as1, ad1, N);
    agg1_kernel<<<(N + 3) / 4, 256, 0, stream>>>(rowptr, colb, as1, ad1, h1, b1, x1e, N);

    // --- Layer 2 ---
    gemm2_kernel<<<(N + 15) / 16, 256, 0, stream>>>(x1e, W2, att_s2, att_d2,
                                                    h2, as2, ad2, N);
    agg2_kernel<<<(N + 3) / 4, 256, 0, stream>>>(rowptr, colb, as2, ad2, h2, b2, out, N);
}